// Round 5
// baseline (311.210 us; speedup 1.0000x reference)
//
#include <hip/hip_runtime.h>

#define DIM 128   // feature dim, fixed per reference
#define GTM 32    // gemm tile rows
#define GTN 128   // gemm tile cols (= DIM, A read once)

// ---------------- edge pass: 4 edges/thread, batched atomics ----------------
// local[e] = this edge's rank among edges sharing its dst (returned atomic value).
// int4 loads for src/dst, 8 atomics in flight per thread, int4 store of slots.
__global__ __launch_bounds__(256) void k_edge_pass(const int* __restrict__ src,
                                                   const int* __restrict__ dst,
                                                   int* __restrict__ deg_out,
                                                   int* __restrict__ cnt,
                                                   int* __restrict__ local, int E) {
    int t = blockIdx.x * 256 + threadIdx.x;
    int nq = E >> 2;
    if (t < nq) {
        int4 s4 = ((const int4*)src)[t];
        int4 d4 = ((const int4*)dst)[t];
        atomicAdd(&deg_out[s4.x], 1);
        atomicAdd(&deg_out[s4.y], 1);
        atomicAdd(&deg_out[s4.z], 1);
        atomicAdd(&deg_out[s4.w], 1);
        int4 r;
        r.x = atomicAdd(&cnt[d4.x], 1);
        r.y = atomicAdd(&cnt[d4.y], 1);
        r.z = atomicAdd(&cnt[d4.z], 1);
        r.w = atomicAdd(&cnt[d4.w], 1);
        ((int4*)local)[t] = r;
    }
    // tail (E % 4 edges)
    int tail = E & 3;
    if (t < tail) {
        int e = (nq << 2) + t;
        atomicAdd(&deg_out[src[e]], 1);
        local[e] = atomicAdd(&cnt[dst[e]], 1);
    }
}

// ---------------- scan step 1: per-block sums of cnt ----------------
__global__ __launch_bounds__(256) void k_block_reduce(const int* __restrict__ deg,
                                                      int* __restrict__ bsum, int N) {
    __shared__ int wsum[4];
    int i = blockIdx.x * 256 + threadIdx.x;
    int x = (i < N) ? deg[i] : 0;
    #pragma unroll
    for (int off = 32; off > 0; off >>= 1) x += __shfl_down(x, off, 64);
    int lane = threadIdx.x & 63, wave = threadIdx.x >> 6;
    if (lane == 0) wsum[wave] = x;
    __syncthreads();
    if (threadIdx.x == 0) bsum[blockIdx.x] = wsum[0] + wsum[1] + wsum[2] + wsum[3];
}

// ---------------- scan step 2: exclusive scan of block sums (1 block) ----------------
__global__ __launch_bounds__(256) void k_scan_small(const int* __restrict__ bsum,
                                                    int* __restrict__ bpre, int B) {
    __shared__ int wsum[4];
    __shared__ int carry_s;
    if (threadIdx.x == 0) carry_s = 0;
    __syncthreads();
    int lane = threadIdx.x & 63, wave = threadIdx.x >> 6;
    for (int base = 0; base < B; base += 256) {
        int i = base + threadIdx.x;
        int x = (i < B) ? bsum[i] : 0;
        int orig = x;
        #pragma unroll
        for (int off = 1; off < 64; off <<= 1) {
            int y = __shfl_up(x, off, 64);
            if (lane >= off) x += y;
        }
        if (lane == 63) wsum[wave] = x;
        __syncthreads();
        if (threadIdx.x == 0) {
            int s = 0;
            for (int w = 0; w < 4; ++w) { int t = wsum[w]; wsum[w] = s; s += t; }
        }
        __syncthreads();
        x += wsum[wave] + carry_s;
        if (i < B) bpre[i] = x - orig;
        __syncthreads();
        if (threadIdx.x == 255) carry_s = x;
        __syncthreads();
    }
}

// ---------------- scan step 3: row_off + both norms (fused) ----------------
__global__ __launch_bounds__(256) void k_scan_final(const int* __restrict__ cnt,
                                                    const int* __restrict__ deg_out,
                                                    const int* __restrict__ bpre,
                                                    int* __restrict__ row_off,
                                                    float* __restrict__ norm_src,
                                                    float* __restrict__ norm_dst, int N) {
    __shared__ int wsum[4];
    int i = blockIdx.x * 256 + threadIdx.x;
    int x = (i < N) ? cnt[i] : 0;
    int orig = x;
    int lane = threadIdx.x & 63, wave = threadIdx.x >> 6;
    #pragma unroll
    for (int off = 1; off < 64; off <<= 1) {
        int y = __shfl_up(x, off, 64);
        if (lane >= off) x += y;
    }
    if (lane == 63) wsum[wave] = x;
    __syncthreads();
    if (threadIdx.x == 0) {
        int s = 0;
        for (int w = 0; w < 4; ++w) { int t = wsum[w]; wsum[w] = s; s += t; }
    }
    __syncthreads();
    x += wsum[wave] + bpre[blockIdx.x];
    if (i < N) {
        row_off[i] = x - orig;                    // exclusive prefix
        int di = orig < 1 ? 1 : orig;             // deg_in clamp
        norm_dst[i] = rsqrtf((float)di);
        int dov = deg_out[i]; if (dov < 1) dov = 1;
        norm_src[i] = rsqrtf((float)dov);
    }
    if (i == N - 1) row_off[N] = x;               // total
}

// ---------------- CSR fill: pure scatter, no atomics ----------------
__global__ __launch_bounds__(256) void k_fill(const int* __restrict__ src,
                                              const int* __restrict__ dst,
                                              const int* __restrict__ row_off,
                                              const int* __restrict__ local,
                                              int* __restrict__ csr_src, int E) {
    int e = blockIdx.x * 256 + threadIdx.x;
    if (e < E) {
        int pos = row_off[dst[e]] + local[e];
        csr_src[pos] = src[e];
    }
}

// ---------------- CSR SpMM: agg[d] = nd[d] * sum_s ns[s]*h[s] ----------------
// 32 lanes per node, float4 per lane; norm_src folded into the gather FMA;
// 8-deep edge unroll + dual acc chains for memory-level parallelism.
__global__ __launch_bounds__(256) void k_spmm(const float* __restrict__ h,
                                              const int* __restrict__ csr_src,
                                              const int* __restrict__ row_off,
                                              const float* __restrict__ norm_src,
                                              const float* __restrict__ norm_dst,
                                              float* __restrict__ agg, int N) {
    int t = blockIdx.x * 256 + threadIdx.x;
    int node = t >> 5;
    int lane = t & 31;
    if (node >= N) return;
    int beg = row_off[node], end = row_off[node + 1];
    float4 acc0 = make_float4(0.f, 0.f, 0.f, 0.f);
    float4 acc1 = make_float4(0.f, 0.f, 0.f, 0.f);
    int i = beg;
    for (; i + 8 <= end; i += 8) {
        int s0 = csr_src[i + 0], s1 = csr_src[i + 1], s2 = csr_src[i + 2], s3 = csr_src[i + 3];
        int s4 = csr_src[i + 4], s5 = csr_src[i + 5], s6 = csr_src[i + 6], s7 = csr_src[i + 7];
        float n0 = norm_src[s0], n1 = norm_src[s1], n2 = norm_src[s2], n3 = norm_src[s3];
        float n4 = norm_src[s4], n5 = norm_src[s5], n6 = norm_src[s6], n7 = norm_src[s7];
        float4 v0 = *((const float4*)(h + (size_t)s0 * DIM) + lane);
        float4 v1 = *((const float4*)(h + (size_t)s1 * DIM) + lane);
        float4 v2 = *((const float4*)(h + (size_t)s2 * DIM) + lane);
        float4 v3 = *((const float4*)(h + (size_t)s3 * DIM) + lane);
        float4 v4 = *((const float4*)(h + (size_t)s4 * DIM) + lane);
        float4 v5 = *((const float4*)(h + (size_t)s5 * DIM) + lane);
        float4 v6 = *((const float4*)(h + (size_t)s6 * DIM) + lane);
        float4 v7 = *((const float4*)(h + (size_t)s7 * DIM) + lane);
        acc0.x += v0.x * n0; acc0.y += v0.y * n0; acc0.z += v0.z * n0; acc0.w += v0.w * n0;
        acc1.x += v1.x * n1; acc1.y += v1.y * n1; acc1.z += v1.z * n1; acc1.w += v1.w * n1;
        acc0.x += v2.x * n2; acc0.y += v2.y * n2; acc0.z += v2.z * n2; acc0.w += v2.w * n2;
        acc1.x += v3.x * n3; acc1.y += v3.y * n3; acc1.z += v3.z * n3; acc1.w += v3.w * n3;
        acc0.x += v4.x * n4; acc0.y += v4.y * n4; acc0.z += v4.z * n4; acc0.w += v4.w * n4;
        acc1.x += v5.x * n5; acc1.y += v5.y * n5; acc1.z += v5.z * n5; acc1.w += v5.w * n5;
        acc0.x += v6.x * n6; acc0.y += v6.y * n6; acc0.z += v6.z * n6; acc0.w += v6.w * n6;
        acc1.x += v7.x * n7; acc1.y += v7.y * n7; acc1.z += v7.z * n7; acc1.w += v7.w * n7;
    }
    for (; i + 4 <= end; i += 4) {
        int s0 = csr_src[i + 0], s1 = csr_src[i + 1], s2 = csr_src[i + 2], s3 = csr_src[i + 3];
        float n0 = norm_src[s0], n1 = norm_src[s1], n2 = norm_src[s2], n3 = norm_src[s3];
        float4 v0 = *((const float4*)(h + (size_t)s0 * DIM) + lane);
        float4 v1 = *((const float4*)(h + (size_t)s1 * DIM) + lane);
        float4 v2 = *((const float4*)(h + (size_t)s2 * DIM) + lane);
        float4 v3 = *((const float4*)(h + (size_t)s3 * DIM) + lane);
        acc0.x += v0.x * n0; acc0.y += v0.y * n0; acc0.z += v0.z * n0; acc0.w += v0.w * n0;
        acc1.x += v1.x * n1; acc1.y += v1.y * n1; acc1.z += v1.z * n1; acc1.w += v1.w * n1;
        acc0.x += v2.x * n2; acc0.y += v2.y * n2; acc0.z += v2.z * n2; acc0.w += v2.w * n2;
        acc1.x += v3.x * n3; acc1.y += v3.y * n3; acc1.z += v3.z * n3; acc1.w += v3.w * n3;
    }
    for (; i < end; ++i) {
        int s0 = csr_src[i];
        float n0 = norm_src[s0];
        float4 v0 = *((const float4*)(h + (size_t)s0 * DIM) + lane);
        acc0.x += v0.x * n0; acc0.y += v0.y * n0; acc0.z += v0.z * n0; acc0.w += v0.w * n0;
    }
    float nd = norm_dst[node];
    float4 o;
    o.x = (acc0.x + acc1.x) * nd;
    o.y = (acc0.y + acc1.y) * nd;
    o.z = (acc0.z + acc1.z) * nd;
    o.w = (acc0.w + acc1.w) * nd;
    *((float4*)(agg + (size_t)node * DIM) + lane) = o;
}

// ---------------- fused: out = relu(agg @ W + b) ----------------
// 32x128 tile, 256 threads, 4x4 acc/thread. Full W (64 KB) staged once,
// A in 64-k chunks (stride 68). 72.7 KB LDS -> 2 blocks/CU.
__global__ __launch_bounds__(256, 2) void k_gemm_bias_relu(
        const float* __restrict__ A, const float* __restrict__ W,
        const float* __restrict__ bias, float* __restrict__ out, int N) {
    __shared__ float Ws[DIM * GTN];   // [k][c] 64 KB
    __shared__ float As[GTM * 68];    // [r][64-k chunk], stride 68

    const int t = threadIdx.x;
    const int row0 = blockIdx.x * GTM;

    #pragma unroll
    for (int i = 0; i < 16; ++i) {
        int idx = (t + i * 256) * 4;
        *(float4*)(Ws + idx) = *(const float4*)(W + idx);
    }

    const int tx = t & 31;    // col group -> cols tx*4..+3
    const int ty = t >> 5;    // row group -> rows ty*4..+3
    const int c0t = tx * 4;

    float acc[4][4];
    #pragma unroll
    for (int i = 0; i < 4; ++i)
        #pragma unroll
        for (int j = 0; j < 4; ++j) acc[i][j] = 0.f;

    for (int kt = 0; kt < DIM; kt += 64) {
        #pragma unroll
        for (int i = 0; i < 2; ++i) {
            int fidx = (t + i * 256) * 4;
            int r = fidx >> 6;
            int k = fidx & 63;
            int gr = row0 + r;
            float4 v = make_float4(0.f, 0.f, 0.f, 0.f);
            if (gr < N) v = *(const float4*)(A + (size_t)gr * DIM + kt + k);
            *(float4*)(As + r * 68 + k) = v;
        }
        __syncthreads();

        #pragma unroll 4
        for (int k = 0; k < 64; k += 4) {
            float a[4][4];
            float w[4][4];
            #pragma unroll
            for (int i = 0; i < 4; ++i)
                *(float4*)a[i] = *(const float4*)(As + (ty * 4 + i) * 68 + k);
            #pragma unroll
            for (int kk = 0; kk < 4; ++kk)
                *(float4*)w[kk] = *(const float4*)(Ws + (kt + k + kk) * GTN + c0t);
            #pragma unroll
            for (int kk = 0; kk < 4; ++kk)
                #pragma unroll
                for (int i = 0; i < 4; ++i)
                    #pragma unroll
                    for (int j = 0; j < 4; ++j)
                        acc[i][j] += a[i][kk] * w[kk][j];
        }
        __syncthreads();
    }

    float bb[4];
    #pragma unroll
    for (int j = 0; j < 4; ++j) bb[j] = bias[c0t + j];
    #pragma unroll
    for (int i = 0; i < 4; ++i) {
        int gr = row0 + ty * 4 + i;
        if (gr < N) {
            float4 o;
            o.x = fmaxf(acc[i][0] + bb[0], 0.f);
            o.y = fmaxf(acc[i][1] + bb[1], 0.f);
            o.z = fmaxf(acc[i][2] + bb[2], 0.f);
            o.w = fmaxf(acc[i][3] + bb[3], 0.f);
            *(float4*)(out + (size_t)gr * DIM + c0t) = o;
        }
    }
}

static inline size_t align_up(size_t x, size_t a) { return (x + a - 1) & ~(a - 1); }

extern "C" void kernel_launch(void* const* d_in, const int* in_sizes, int n_in,
                              void* d_out, int out_size, void* d_ws, size_t ws_size,
                              hipStream_t stream) {
    const float* features = (const float*)d_in[0];
    const int*   src      = (const int*)d_in[1];
    const int*   dst      = (const int*)d_in[2];
    const float* W1       = (const float*)d_in[3];
    const float* b1       = (const float*)d_in[4];
    const float* W2       = (const float*)d_in[5];
    const float* b2       = (const float*)d_in[6];
    float* out = (float*)d_out;

    const int N = in_sizes[0] / DIM;
    const int E = in_sizes[1];
    const int B = (N + 255) / 256;

    // workspace carve-up
    size_t nodeb = align_up((size_t)N * 4, 256);
    char* p = (char*)d_ws;
    int*   deg_out  = (int*)p;                      p += nodeb;
    int*   cnt      = (int*)p;                      p += nodeb;
    float* norm_src = (float*)p;                    p += nodeb;
    float* norm_dst = (float*)p;                    p += nodeb;
    int*   row_off  = (int*)p;                      p += align_up((size_t)(N + 1) * 4, 256);
    int*   bsum     = (int*)p;                      p += align_up((size_t)B * 4, 256);
    int*   bpre     = (int*)p;                      p += align_up((size_t)B * 4, 256);
    int*   csr_src  = (int*)p;                      p += align_up((size_t)E * 4, 256);
    float* agg      = (float*)p;                    p += (size_t)N * DIM * 4;
    float* h1       = (float*)p;                    p += (size_t)N * DIM * 4;
    // local[E] aliases agg: dead after k_fill, agg first written by k_spmm later
    int*   local    = (int*)agg;

    const int edge_blocks = (E + 255) / 256;
    const int ep_blocks   = ((E >> 2) + 255) / 256;   // 4 edges per thread
    const int spmm_blocks = (int)(((size_t)N * 32 + 255) / 256);
    const int gemm_blocks = (N + GTM - 1) / GTM;

    // graph build: 1.2M atomics total (the floor for two histograms)
    hipMemsetAsync(deg_out, 0, nodeb * 2, stream);  // deg_out, cnt
    k_edge_pass<<<ep_blocks, 256, 0, stream>>>(src, dst, deg_out, cnt, local, E);
    k_block_reduce<<<B, 256, 0, stream>>>(cnt, bsum, N);
    k_scan_small<<<1, 256, 0, stream>>>(bsum, bpre, B);
    k_scan_final<<<B, 256, 0, stream>>>(cnt, deg_out, bpre, row_off, norm_src, norm_dst, N);
    k_fill<<<edge_blocks, 256, 0, stream>>>(src, dst, row_off, local, csr_src, E);

    // layer 1
    k_spmm<<<spmm_blocks, 256, 0, stream>>>(features, csr_src, row_off, norm_src, norm_dst, agg, N);
    k_gemm_bias_relu<<<gemm_blocks, 256, 0, stream>>>(agg, W1, b1, h1, N);

    // layer 2
    k_spmm<<<spmm_blocks, 256, 0, stream>>>(h1, csr_src, row_off, norm_src, norm_dst, agg, N);
    k_gemm_bias_relu<<<gemm_blocks, 256, 0, stream>>>(agg, W2, b2, out, N);
}

// Round 6
// 308.995 us; speedup vs baseline: 1.0072x; 1.0072x over previous
//
#include <hip/hip_runtime.h>

#define DIM 128      // feature dim, fixed per reference
#define GTM 32       // gemm tile rows
#define GTN 128      // gemm tile cols (= DIM, A read once)
#define HB  64       // histogram privatization: blocks/copies
#define HWORDS 25088 // max (N+1)/2 supported by LDS histogram (100,352 B)

// ---------------- LDS-privatized dual histogram + rank capture ----------------
// Each block: slice of edges -> LDS histogram (2x16-bit counters/word).
// dst phase captures per-slice rank (ds_add_rtn); src phase counts only.
// Private copies streamed to global with plain stores -> ~zero global atomics.
__global__ __launch_bounds__(256) void k_hist(const int* __restrict__ src,
                                              const int* __restrict__ dst,
                                              int* __restrict__ local,
                                              unsigned* __restrict__ hist_in,
                                              unsigned* __restrict__ hist_out,
                                              int E, int W2, int slice) {
    __shared__ unsigned h[HWORDS];
    const int t = threadIdx.x;
    const int b = blockIdx.x;
    const int e0 = b * slice;
    const int e1 = min(e0 + slice, E);

    for (int w = t; w < W2; w += 256) h[w] = 0u;
    __syncthreads();
    // dst histogram with rank capture
    for (int e = e0 + t; e < e1; e += 256) {
        int d = dst[e];
        unsigned sh = (unsigned)(d & 1) * 16u;
        unsigned old = atomicAdd(&h[d >> 1], 1u << sh);
        local[e] = (int)((old >> sh) & 0xffffu);
    }
    __syncthreads();
    unsigned* oin = hist_in + (size_t)b * W2;
    for (int w = t; w < W2; w += 256) { oin[w] = h[w]; h[w] = 0u; }
    __syncthreads();
    // src histogram (no rank)
    for (int e = e0 + t; e < e1; e += 256) {
        int s = src[e];
        atomicAdd(&h[s >> 1], 1u << ((unsigned)(s & 1) * 16u));
    }
    __syncthreads();
    unsigned* oout = hist_out + (size_t)b * W2;
    for (int w = t; w < W2; w += 256) oout[w] = h[w];
}

// ---------------- column scan: per-node exclusive prefix across HB copies ----------------
// In-place on hist_in (packed 16-bit halves; per-node prefix < 65536 assumed —
// holds unless a single node has in-degree >= 65536). Totals -> cnt / deg_out.
__global__ __launch_bounds__(256) void k_colscan(unsigned* __restrict__ hist_in,
                                                 const unsigned* __restrict__ hist_out,
                                                 int* __restrict__ cnt,
                                                 int* __restrict__ deg_out,
                                                 int W2, int N, int nb) {
    int w = blockIdx.x * 256 + threadIdx.x;
    if (w >= W2) return;
    unsigned run = 0;
    for (int b = 0; b < nb; ++b) {
        unsigned* p = hist_in + (size_t)b * W2 + w;
        unsigned x = *p;
        *p = run;          // exclusive packed prefix
        run += x;          // halves independent (no carry while each < 65536)
    }
    unsigned run2 = 0;
    #pragma unroll 4
    for (int b = 0; b < nb; ++b) run2 += hist_out[(size_t)b * W2 + w];
    int n0 = w * 2, n1 = n0 + 1;
    cnt[n0] = (int)(run & 0xffffu);
    deg_out[n0] = (int)(run2 & 0xffffu);
    if (n1 < N) {
        cnt[n1] = (int)(run >> 16);
        deg_out[n1] = (int)(run2 >> 16);
    }
}

// ---------------- fallback edge pass (global atomics) for oversized N ----------------
__global__ __launch_bounds__(256) void k_edge_pass_fb(const int* __restrict__ src,
                                                      const int* __restrict__ dst,
                                                      int* __restrict__ deg_out,
                                                      int* __restrict__ cnt,
                                                      int* __restrict__ local, int E) {
    int e = blockIdx.x * 256 + threadIdx.x;
    if (e < E) {
        atomicAdd(&deg_out[src[e]], 1);
        local[e] = atomicAdd(&cnt[dst[e]], 1);
    }
}

// ---------------- scan step 1: per-block sums of cnt ----------------
__global__ __launch_bounds__(256) void k_block_reduce(const int* __restrict__ deg,
                                                      int* __restrict__ bsum, int N) {
    __shared__ int wsum[4];
    int i = blockIdx.x * 256 + threadIdx.x;
    int x = (i < N) ? deg[i] : 0;
    #pragma unroll
    for (int off = 32; off > 0; off >>= 1) x += __shfl_down(x, off, 64);
    int lane = threadIdx.x & 63, wave = threadIdx.x >> 6;
    if (lane == 0) wsum[wave] = x;
    __syncthreads();
    if (threadIdx.x == 0) bsum[blockIdx.x] = wsum[0] + wsum[1] + wsum[2] + wsum[3];
}

// ---------------- scan step 2: exclusive scan of block sums (1 block) ----------------
__global__ __launch_bounds__(256) void k_scan_small(const int* __restrict__ bsum,
                                                    int* __restrict__ bpre, int B) {
    __shared__ int wsum[4];
    __shared__ int carry_s;
    if (threadIdx.x == 0) carry_s = 0;
    __syncthreads();
    int lane = threadIdx.x & 63, wave = threadIdx.x >> 6;
    for (int base = 0; base < B; base += 256) {
        int i = base + threadIdx.x;
        int x = (i < B) ? bsum[i] : 0;
        int orig = x;
        #pragma unroll
        for (int off = 1; off < 64; off <<= 1) {
            int y = __shfl_up(x, off, 64);
            if (lane >= off) x += y;
        }
        if (lane == 63) wsum[wave] = x;
        __syncthreads();
        if (threadIdx.x == 0) {
            int s = 0;
            for (int w = 0; w < 4; ++w) { int t = wsum[w]; wsum[w] = s; s += t; }
        }
        __syncthreads();
        x += wsum[wave] + carry_s;
        if (i < B) bpre[i] = x - orig;
        __syncthreads();
        if (threadIdx.x == 255) carry_s = x;
        __syncthreads();
    }
}

// ---------------- scan step 3: row_off + both norms (fused) ----------------
__global__ __launch_bounds__(256) void k_scan_final(const int* __restrict__ cnt,
                                                    const int* __restrict__ deg_out,
                                                    const int* __restrict__ bpre,
                                                    int* __restrict__ row_off,
                                                    float* __restrict__ norm_src,
                                                    float* __restrict__ norm_dst, int N) {
    __shared__ int wsum[4];
    int i = blockIdx.x * 256 + threadIdx.x;
    int x = (i < N) ? cnt[i] : 0;
    int orig = x;
    int lane = threadIdx.x & 63, wave = threadIdx.x >> 6;
    #pragma unroll
    for (int off = 1; off < 64; off <<= 1) {
        int y = __shfl_up(x, off, 64);
        if (lane >= off) x += y;
    }
    if (lane == 63) wsum[wave] = x;
    __syncthreads();
    if (threadIdx.x == 0) {
        int s = 0;
        for (int w = 0; w < 4; ++w) { int t = wsum[w]; wsum[w] = s; s += t; }
    }
    __syncthreads();
    x += wsum[wave] + bpre[blockIdx.x];
    if (i < N) {
        row_off[i] = x - orig;                    // exclusive prefix
        int di = orig < 1 ? 1 : orig;             // deg_in clamp
        norm_dst[i] = rsqrtf((float)di);
        int dov = deg_out[i]; if (dov < 1) dov = 1;
        norm_src[i] = rsqrtf((float)dov);
    }
    if (i == N - 1) row_off[N] = x;               // total
}

// ---------------- CSR fill: pure scatter, no atomics ----------------
// fast path: pos = row_off[dst] + blockoff(hist_in) + local rank
// fallback (hist_in == nullptr): pos = row_off[dst] + local (global-atomic rank)
__global__ __launch_bounds__(256) void k_fill(const int* __restrict__ src,
                                              const int* __restrict__ dst,
                                              const int* __restrict__ row_off,
                                              const int* __restrict__ local,
                                              const unsigned* __restrict__ hist_in,
                                              int* __restrict__ csr_src,
                                              int E, int W2, int slice) {
    int e = blockIdx.x * 256 + threadIdx.x;
    if (e < E) {
        int d = dst[e];
        int pos = row_off[d] + local[e];
        if (hist_in) {
            int b = e / slice;
            unsigned bo = (hist_in[(size_t)b * W2 + (d >> 1)] >> ((unsigned)(d & 1) * 16u)) & 0xffffu;
            pos += (int)bo;
        }
        csr_src[pos] = src[e];
    }
}

// ---------------- CSR SpMM: agg[d] = nd[d] * sum_s ns[s]*h[s] ----------------
// 32 lanes per node, float4 per lane; norm_src folded into the gather FMA;
// 4-deep edge unroll (R4-proven; 8-deep regressed occupancy/ILP balance).
__global__ __launch_bounds__(256) void k_spmm(const float* __restrict__ h,
                                              const int* __restrict__ csr_src,
                                              const int* __restrict__ row_off,
                                              const float* __restrict__ norm_src,
                                              const float* __restrict__ norm_dst,
                                              float* __restrict__ agg, int N) {
    int t = blockIdx.x * 256 + threadIdx.x;
    int node = t >> 5;
    int lane = t & 31;
    if (node >= N) return;
    int beg = row_off[node], end = row_off[node + 1];
    float4 acc = make_float4(0.f, 0.f, 0.f, 0.f);
    int i = beg;
    for (; i + 4 <= end; i += 4) {
        int s0 = csr_src[i];
        int s1 = csr_src[i + 1];
        int s2 = csr_src[i + 2];
        int s3 = csr_src[i + 3];
        float n0 = norm_src[s0], n1 = norm_src[s1], n2 = norm_src[s2], n3 = norm_src[s3];
        float4 v0 = *((const float4*)(h + (size_t)s0 * DIM) + lane);
        float4 v1 = *((const float4*)(h + (size_t)s1 * DIM) + lane);
        float4 v2 = *((const float4*)(h + (size_t)s2 * DIM) + lane);
        float4 v3 = *((const float4*)(h + (size_t)s3 * DIM) + lane);
        acc.x += v0.x * n0; acc.y += v0.y * n0; acc.z += v0.z * n0; acc.w += v0.w * n0;
        acc.x += v1.x * n1; acc.y += v1.y * n1; acc.z += v1.z * n1; acc.w += v1.w * n1;
        acc.x += v2.x * n2; acc.y += v2.y * n2; acc.z += v2.z * n2; acc.w += v2.w * n2;
        acc.x += v3.x * n3; acc.y += v3.y * n3; acc.z += v3.z * n3; acc.w += v3.w * n3;
    }
    for (; i < end; ++i) {
        int s0 = csr_src[i];
        float n0 = norm_src[s0];
        float4 v0 = *((const float4*)(h + (size_t)s0 * DIM) + lane);
        acc.x += v0.x * n0; acc.y += v0.y * n0; acc.z += v0.z * n0; acc.w += v0.w * n0;
    }
    float nd = norm_dst[node];
    acc.x *= nd; acc.y *= nd; acc.z *= nd; acc.w *= nd;
    *((float4*)(agg + (size_t)node * DIM) + lane) = acc;
}

// ---------------- fused: out = relu(agg @ W + b) ----------------
// 32x128 tile, 256 threads, 4x4 acc/thread. Full W (64 KB) staged once,
// A in 64-k chunks (stride 68). 72.7 KB LDS -> 2 blocks/CU.
__global__ __launch_bounds__(256, 2) void k_gemm_bias_relu(
        const float* __restrict__ A, const float* __restrict__ W,
        const float* __restrict__ bias, float* __restrict__ out, int N) {
    __shared__ float Ws[DIM * GTN];   // [k][c] 64 KB
    __shared__ float As[GTM * 68];    // [r][64-k chunk], stride 68

    const int t = threadIdx.x;
    const int row0 = blockIdx.x * GTM;

    #pragma unroll
    for (int i = 0; i < 16; ++i) {
        int idx = (t + i * 256) * 4;
        *(float4*)(Ws + idx) = *(const float4*)(W + idx);
    }

    const int tx = t & 31;    // col group -> cols tx*4..+3
    const int ty = t >> 5;    // row group -> rows ty*4..+3
    const int c0t = tx * 4;

    float acc[4][4];
    #pragma unroll
    for (int i = 0; i < 4; ++i)
        #pragma unroll
        for (int j = 0; j < 4; ++j) acc[i][j] = 0.f;

    for (int kt = 0; kt < DIM; kt += 64) {
        #pragma unroll
        for (int i = 0; i < 2; ++i) {
            int fidx = (t + i * 256) * 4;
            int r = fidx >> 6;
            int k = fidx & 63;
            int gr = row0 + r;
            float4 v = make_float4(0.f, 0.f, 0.f, 0.f);
            if (gr < N) v = *(const float4*)(A + (size_t)gr * DIM + kt + k);
            *(float4*)(As + r * 68 + k) = v;
        }
        __syncthreads();

        #pragma unroll 4
        for (int k = 0; k < 64; k += 4) {
            float a[4][4];
            float w[4][4];
            #pragma unroll
            for (int i = 0; i < 4; ++i)
                *(float4*)a[i] = *(const float4*)(As + (ty * 4 + i) * 68 + k);
            #pragma unroll
            for (int kk = 0; kk < 4; ++kk)
                *(float4*)w[kk] = *(const float4*)(Ws + (kt + k + kk) * GTN + c0t);
            #pragma unroll
            for (int kk = 0; kk < 4; ++kk)
                #pragma unroll
                for (int i = 0; i < 4; ++i)
                    #pragma unroll
                    for (int j = 0; j < 4; ++j)
                        acc[i][j] += a[i][kk] * w[kk][j];
        }
        __syncthreads();
    }

    float bb[4];
    #pragma unroll
    for (int j = 0; j < 4; ++j) bb[j] = bias[c0t + j];
    #pragma unroll
    for (int i = 0; i < 4; ++i) {
        int gr = row0 + ty * 4 + i;
        if (gr < N) {
            float4 o;
            o.x = fmaxf(acc[i][0] + bb[0], 0.f);
            o.y = fmaxf(acc[i][1] + bb[1], 0.f);
            o.z = fmaxf(acc[i][2] + bb[2], 0.f);
            o.w = fmaxf(acc[i][3] + bb[3], 0.f);
            *(float4*)(out + (size_t)gr * DIM + c0t) = o;
        }
    }
}

static inline size_t align_up(size_t x, size_t a) { return (x + a - 1) & ~(a - 1); }

extern "C" void kernel_launch(void* const* d_in, const int* in_sizes, int n_in,
                              void* d_out, int out_size, void* d_ws, size_t ws_size,
                              hipStream_t stream) {
    const float* features = (const float*)d_in[0];
    const int*   src      = (const int*)d_in[1];
    const int*   dst      = (const int*)d_in[2];
    const float* W1       = (const float*)d_in[3];
    const float* b1       = (const float*)d_in[4];
    const float* W2       = (const float*)d_in[5];
    const float* b2       = (const float*)d_in[6];
    float* out = (float*)d_out;

    const int N = in_sizes[0] / DIM;
    const int E = in_sizes[1];
    const int B = (N + 255) / 256;
    const int W2w = (N + 1) >> 1;                 // packed histogram words
    const int slice = (E + HB - 1) / HB;

    // workspace carve-up
    size_t nodeb = align_up((size_t)N * 4, 256);
    char* p = (char*)d_ws;
    int*   deg_out  = (int*)p;                      p += nodeb;
    int*   cnt      = (int*)p;                      p += nodeb;
    float* norm_src = (float*)p;                    p += nodeb;
    float* norm_dst = (float*)p;                    p += nodeb;
    int*   row_off  = (int*)p;                      p += align_up((size_t)(N + 1) * 4, 256);
    int*   bsum     = (int*)p;                      p += align_up((size_t)B * 4, 256);
    int*   bpre     = (int*)p;                      p += align_up((size_t)B * 4, 256);
    int*   csr_src  = (int*)p;                      p += align_up((size_t)E * 4, 256);
    float* agg      = (float*)p;                    p += (size_t)N * DIM * 4;
    float* h1       = (float*)p;                    p += (size_t)N * DIM * 4;
    // aliases into agg (all dead before k_spmm first writes agg):
    char* ap = (char*)agg;
    int*      local    = (int*)ap;                  ap += align_up((size_t)E * 4, 256);
    unsigned* hist_in  = (unsigned*)ap;             ap += align_up((size_t)HB * W2w * 4, 256);
    unsigned* hist_out = (unsigned*)ap;

    const int edge_blocks = (E + 255) / 256;
    const int spmm_blocks = (int)(((size_t)N * 32 + 255) / 256);
    const int gemm_blocks = (N + GTM - 1) / GTM;
    const int cs_blocks   = (W2w + 255) / 256;

    const bool fast = (W2w <= HWORDS) &&
        ((size_t)E * 4 + 2 * (size_t)HB * W2w * 4 + 512 <= (size_t)N * DIM * 4);

    if (fast) {
        // atomic-free graph build: LDS-private histograms + column scan
        k_hist<<<HB, 256, 0, stream>>>(src, dst, local, hist_in, hist_out, E, W2w, slice);
        k_colscan<<<cs_blocks, 256, 0, stream>>>(hist_in, hist_out, cnt, deg_out, W2w, N, HB);
        k_block_reduce<<<B, 256, 0, stream>>>(cnt, bsum, N);
        k_scan_small<<<1, 256, 0, stream>>>(bsum, bpre, B);
        k_scan_final<<<B, 256, 0, stream>>>(cnt, deg_out, bpre, row_off, norm_src, norm_dst, N);
        k_fill<<<edge_blocks, 256, 0, stream>>>(src, dst, row_off, local, hist_in, csr_src, E, W2w, slice);
    } else {
        hipMemsetAsync(deg_out, 0, nodeb * 2, stream);  // deg_out, cnt
        k_edge_pass_fb<<<edge_blocks, 256, 0, stream>>>(src, dst, deg_out, cnt, local, E);
        k_block_reduce<<<B, 256, 0, stream>>>(cnt, bsum, N);
        k_scan_small<<<1, 256, 0, stream>>>(bsum, bpre, B);
        k_scan_final<<<B, 256, 0, stream>>>(cnt, deg_out, bpre, row_off, norm_src, norm_dst, N);
        k_fill<<<edge_blocks, 256, 0, stream>>>(src, dst, row_off, local, (const unsigned*)nullptr, csr_src, E, W2w, slice);
    }

    // layer 1
    k_spmm<<<spmm_blocks, 256, 0, stream>>>(features, csr_src, row_off, norm_src, norm_dst, agg, N);
    k_gemm_bias_relu<<<gemm_blocks, 256, 0, stream>>>(agg, W1, b1, h1, N);

    // layer 2
    k_spmm<<<spmm_blocks, 256, 0, stream>>>(h1, csr_src, row_off, norm_src, norm_dst, agg, N);
    k_gemm_bias_relu<<<gemm_blocks, 256, 0, stream>>>(agg, W2, b2, out, N);
}